// Round 9
// baseline (207.924 us; speedup 1.0000x reference)
//
#include <hip/hip_runtime.h>
#include <hip/hip_bf16.h>
#include <stdint.h>

typedef __bf16 bf16x8 __attribute__((ext_vector_type(8)));
typedef float f32x4 __attribute__((ext_vector_type(4)));
typedef unsigned short us4v __attribute__((ext_vector_type(4)));
typedef unsigned short us8v __attribute__((ext_vector_type(8)));

#define B_   2
#define T_   2048
#define C_   1024
#define NH_  16
#define HD_  64

__device__ __forceinline__ unsigned short f2bf(float f) {
  unsigned int u = __builtin_bit_cast(unsigned int, f);
  u += 0x7fffu + ((u >> 16) & 1u);           // RNE
  return (unsigned short)(u >> 16);
}
__device__ __forceinline__ float bf2f(unsigned short u) {
  unsigned int x = ((unsigned int)u) << 16;
  return __builtin_bit_cast(float, x);
}

__device__ __forceinline__ void gload16(const void* g, void* l) {
  __builtin_amdgcn_global_load_lds(
      (const __attribute__((address_space(1))) unsigned int*)g,
      (__attribute__((address_space(3))) unsigned int*)l, 16, 0, 0);
}

__device__ __forceinline__ f32x4 mfma16(bf16x8 a, bf16x8 b, f32x4 c) {
  return __builtin_amdgcn_mfma_f32_16x16x32_bf16(a, b, c, 0, 0, 0);
}

// ---------------- cast / transpose ----------------
__global__ __launch_bounds__(256) void cast_x_kernel(const float4* __restrict__ in,
                                                     us4v* __restrict__ out) {
  int i = blockIdx.x * 256 + threadIdx.x;
  float4 f = in[i];
  us4v o; o[0] = f2bf(f.x); o[1] = f2bf(f.y); o[2] = f2bf(f.z); o[3] = f2bf(f.w);
  out[i] = o;
}

// w: (K x N) fp32 row-major  ->  wT: (N x K) bf16 row-major
__global__ __launch_bounds__(256) void transpose_cast_kernel(const float* __restrict__ w,
                                                             unsigned short* __restrict__ wT,
                                                             int K, int N) {
  __shared__ float tile[32][33];
  int n0 = blockIdx.x * 32, k0 = blockIdx.y * 32;
  int tx = threadIdx.x, ty = threadIdx.y;   // 32 x 8
  #pragma unroll
  for (int i = 0; i < 4; ++i)
    tile[ty + 8*i][tx] = w[(size_t)(k0 + ty + 8*i) * N + n0 + tx];
  __syncthreads();
  #pragma unroll
  for (int i = 0; i < 4; ++i)
    wT[(size_t)(n0 + ty + 8*i) * K + k0 + tx] = f2bf(tile[tx][ty + 8*i]);
}

// ---------------- GEMM core (verified round 0) ----------------
__device__ __forceinline__ void gemm_core(const unsigned short* __restrict__ A,
                                          const unsigned short* __restrict__ Bt,
                                          int K, int m0, int n0,
                                          unsigned short* lA, unsigned short* lB,
                                          f32x4 acc[4][4]) {
  const int t = threadIdx.x;
  const int lane = t & 63, w = t >> 6;
  const int wm = w >> 1, wn = w & 1;
  const int g = lane >> 4, r16 = lane & 15;
  #pragma unroll
  for (int i = 0; i < 4; ++i)
    #pragma unroll
    for (int j = 0; j < 4; ++j) acc[i][j] = (f32x4){0.f, 0.f, 0.f, 0.f};

  for (int k0 = 0; k0 < K; k0 += 64) {
    #pragma unroll
    for (int i = 0; i < 4; ++i) {
      int slot = i * 256 + t;
      int r = slot >> 3, p = slot & 7;
      int q = p ^ (r & 7);
      gload16(A  + (size_t)(m0 + r) * K + k0 + q * 8, lA + slot * 8);
      gload16(Bt + (size_t)(n0 + r) * K + k0 + q * 8, lB + slot * 8);
    }
    asm volatile("s_waitcnt vmcnt(0)" ::: "memory");
    __syncthreads();

    bf16x8 af[4][2], bfr[4][2];
    #pragma unroll
    for (int mi = 0; mi < 4; ++mi)
      #pragma unroll
      for (int kk = 0; kk < 2; ++kk) {
        int r = wm * 64 + mi * 16 + r16;
        int ps = (kk * 4 + g) ^ (r & 7);
        af[mi][kk] = *(const bf16x8*)(lA + r * 64 + ps * 8);
      }
    #pragma unroll
    for (int ni = 0; ni < 4; ++ni)
      #pragma unroll
      for (int kk = 0; kk < 2; ++kk) {
        int r = wn * 64 + ni * 16 + r16;
        int ps = (kk * 4 + g) ^ (r & 7);
        bfr[ni][kk] = *(const bf16x8*)(lB + r * 64 + ps * 8);
      }
    #pragma unroll
    for (int mi = 0; mi < 4; ++mi)
      #pragma unroll
      for (int ni = 0; ni < 4; ++ni)
        #pragma unroll
        for (int kk = 0; kk < 2; ++kk)
          acc[mi][ni] = mfma16(af[mi][kk], bfr[ni][kk], acc[mi][ni]);
    __syncthreads();
  }
}

// XCD-aware bijective swizzle of the linear workgroup id (nwg % 8 == 0)
__device__ __forceinline__ int xcd_swz(int flat, int nwg) {
  int cpx = nwg >> 3;
  return (flat & 7) * cpx + (flat >> 3);
}

__global__ __launch_bounds__(256) void gemm_qkv_kernel(const unsigned short* __restrict__ xb,
                                                       const unsigned short* __restrict__ wT,
                                                       unsigned short* __restrict__ qb,
                                                       unsigned short* __restrict__ kb,
                                                       unsigned short* __restrict__ vb) {
  __shared__ unsigned short lA[128 * 64];
  __shared__ unsigned short lB[128 * 64];
  f32x4 acc[4][4];
  const int nbx = 3 * C_ / 128;
  int flat = xcd_swz(blockIdx.y * nbx + blockIdx.x, nbx * ((B_ * T_) / 128));
  const int m0 = (flat / nbx) * 128, n0 = (flat % nbx) * 128;
  gemm_core(xb, wT, C_, m0, n0, lA, lB, acc);
  const int t = threadIdx.x, lane = t & 63, w = t >> 6;
  const int wm = w >> 1, wn = w & 1, g = lane >> 4, r16 = lane & 15;
  #pragma unroll
  for (int mi = 0; mi < 4; ++mi)
    #pragma unroll
    for (int ni = 0; ni < 4; ++ni)
      #pragma unroll
      for (int j = 0; j < 4; ++j) {
        int gm = m0 + wm * 64 + mi * 16 + g * 4 + j;
        int gn = n0 + wn * 64 + ni * 16 + r16;
        int b = gm >> 11, tt = gm & 2047;
        int s = gn >> 10, rem = gn & 1023;
        int h = rem >> 6, d = rem & 63;
        unsigned short val = f2bf(acc[mi][ni][j]);
        size_t idx = ((size_t)(b * NH_ + h) * T_ + tt) * HD_ + d;
        if (s == 0)      qb[idx] = val;
        else if (s == 1) kb[idx] = val;
        else             vb[idx] = val;
      }
}

__global__ __launch_bounds__(256) void gemm_proj_kernel(const unsigned short* __restrict__ ab,
                                                        const unsigned short* __restrict__ wT,
                                                        float* __restrict__ out) {
  __shared__ unsigned short lA[128 * 64];
  __shared__ unsigned short lB[128 * 64];
  f32x4 acc[4][4];
  const int nbx = C_ / 128;
  int flat = xcd_swz(blockIdx.y * nbx + blockIdx.x, nbx * ((B_ * T_) / 128));
  const int m0 = (flat / nbx) * 128, n0 = (flat % nbx) * 128;
  gemm_core(ab, wT, C_, m0, n0, lA, lB, acc);
  const int t = threadIdx.x, lane = t & 63, w = t >> 6;
  const int wm = w >> 1, wn = w & 1, g = lane >> 4, r16 = lane & 15;
  #pragma unroll
  for (int mi = 0; mi < 4; ++mi)
    #pragma unroll
    for (int ni = 0; ni < 4; ++ni)
      #pragma unroll
      for (int j = 0; j < 4; ++j) {
        int gm = m0 + wm * 64 + mi * 16 + g * 4 + j;
        int gn = n0 + wn * 64 + ni * 16 + r16;
        out[(size_t)gm * C_ + gn] = acc[mi][ni][j];
      }
}

// ---------------- Flash attention v9 ----------------
// v7 structure (pairs, 256 thr, 4 waves x 32 q-rows, K gload_lds, V reg->LDS
// transposed conflict-free) with KVBLK=128 epochs: each barrier epoch stages
// and computes TWO 64-kv subtiles — one vmcnt+barrier per 2 tiles, ONE unified
// softmax over 128 columns, 2x prefetch distance.
// LDS (us): K0 [0,8192) K1 [8192,16384) V0 [16384,24576) V1 [24576,32768).
// K tile: [128 kv][64 d], granule swizzle q = p ^ (r&7).
// V tile: Vt[d=64][128 cols], col' = kvhalf*64 + perm(kv_local), slot swizzle.
__global__ __launch_bounds__(256, 2) void attn_kernel(const unsigned short* __restrict__ qb,
                                                      const unsigned short* __restrict__ kb,
                                                      const unsigned short* __restrict__ vb,
                                                      unsigned short* __restrict__ ao) {
  __shared__ unsigned short LDS[32768];
  const int pairIdx = blockIdx.x, bh = blockIdx.y;
  const int t = threadIdx.x, lane = t & 63, w4 = t >> 6;   // 0..3
  const int g = lane >> 4, r16 = lane & 15;
  const int sel = w4 >> 1, halfsel = w4 & 1;
  const int tile = sel ? (31 - pairIdx) : pairIdx;
  const int qt0 = tile * 64 + halfsel * 32;
  const int myNt = tile + 1;
  const int ntMax = 32 - pairIdx;
  const int epochs = (ntMax + 1) >> 1;

  const unsigned short* Q  = qb + (size_t)bh * (T_ * HD_);
  const unsigned short* Kp = kb + (size_t)bh * (T_ * HD_);
  const unsigned short* Vp = vb + (size_t)bh * (T_ * HD_);

  // Q fragments (B-operand: lane holds Q[q=r16][k-octet g]), two halves, pre-scaled 1/8
  bf16x8 qf[2][2];
  #pragma unroll
  for (int h = 0; h < 2; ++h) {
    int qrow = qt0 + h * 16 + r16;
    #pragma unroll
    for (int kk = 0; kk < 2; ++kk) {
      us8v raw = *(const us8v*)(Q + (size_t)qrow * HD_ + kk * 32 + g * 8);
      bf16x8 qv;
      #pragma unroll
      for (int j = 0; j < 8; ++j) qv[j] = (__bf16)(bf2f(raw[j]) * 0.125f);
      qf[h][kk] = qv;
    }
  }

  f32x4 o[2][4];
  #pragma unroll
  for (int h = 0; h < 2; ++h)
    #pragma unroll
    for (int c = 0; c < 4; ++c) o[h][c] = (f32x4){0.f, 0.f, 0.f, 0.f};
  float mrun[2] = {-__builtin_inff(), -__builtin_inff()};
  float lrun[2] = {0.f, 0.f};

  // staging constants
  // K: thread stages slots t+256i, i=0..3 (row r=slot>>3 in [0,128), swizzled granule)
  const int kr0 = (t +   0) >> 3, kp0 = (t & 7) ^ (kr0 & 7);
  const int kr1 = (t + 256) >> 3, kp1 = (t & 7) ^ (kr1 & 7);
  const int kr2 = (t + 512) >> 3, kp2 = (t & 7) ^ (kr2 & 7);
  const int kr3 = (t + 768) >> 3, kp3 = (t & 7) ^ (kr3 & 7);
  // V: wave w4 owns d-octets {2w4, 2w4+1}; lane owns kv rows lane, lane+64.
  // col'(kv_local): kv = 32a+16H+4G+E -> col' = 32a+8G+4H+E (bijective/step)
  const int colp = (lane & 32) | ((lane & 12) << 1) | ((lane >> 2) & 4) | (lane & 3);
  const int cslot = colp >> 3, cwithin = colp & 7;
  const int oct0 = 2 * w4, oct1 = 2 * w4 + 1;

  // prologue: epoch-0 loads (K DMA then V regs)
  gload16(Kp + (size_t)kr0 * HD_ + kp0 * 8, LDS + (t +   0) * 8);
  gload16(Kp + (size_t)kr1 * HD_ + kp1 * 8, LDS + (t + 256) * 8);
  gload16(Kp + (size_t)kr2 * HD_ + kp2 * 8, LDS + (t + 512) * 8);
  gload16(Kp + (size_t)kr3 * HD_ + kp3 * 8, LDS + (t + 768) * 8);
  us8v nv00 = *(const us8v*)(Vp + (size_t)lane * HD_ + oct0 * 8);
  us8v nv01 = *(const us8v*)(Vp + (size_t)lane * HD_ + oct1 * 8);
  us8v nv10 = *(const us8v*)(Vp + (size_t)(lane + 64) * HD_ + oct0 * 8);
  us8v nv11 = *(const us8v*)(Vp + (size_t)(lane + 64) * HD_ + oct1 * 8);

  for (int e = 0; e < epochs; ++e) {
    const int cur = e & 1;
    const unsigned short* Kl = LDS + cur * 8192;
    unsigned short* Vt = LDS + 16384 + cur * 8192;

    asm volatile("s_waitcnt vmcnt(0)" ::: "memory");   // K[e] in LDS, V[e] in regs
    #pragma unroll
    for (int u = 0; u < 8; ++u) {
      int d = oct0 * 8 + u;                            // d&7 == u
      Vt[d * 128 + ((cslot ^ u) << 3) + cwithin] = nv00[u];
    }
    #pragma unroll
    for (int u = 0; u < 8; ++u) {
      int d = oct1 * 8 + u;
      Vt[d * 128 + ((cslot ^ u) << 3) + cwithin] = nv01[u];
    }
    #pragma unroll
    for (int u = 0; u < 8; ++u) {
      int d = oct0 * 8 + u;
      Vt[d * 128 + 64 + ((cslot ^ u) << 3) + cwithin] = nv10[u];
    }
    #pragma unroll
    for (int u = 0; u < 8; ++u) {
      int d = oct1 * 8 + u;
      Vt[d * 128 + 64 + ((cslot ^ u) << 3) + cwithin] = nv11[u];
    }
    __syncthreads();

    if (e + 1 < epochs) {    // issue next-epoch loads (land in buf cur^1)
      const int kw = (e + 1) * 128;
      unsigned short* Kn = LDS + (cur ^ 1) * 8192;
      gload16(Kp + (size_t)(kw + kr0) * HD_ + kp0 * 8, Kn + (t +   0) * 8);
      gload16(Kp + (size_t)(kw + kr1) * HD_ + kp1 * 8, Kn + (t + 256) * 8);
      gload16(Kp + (size_t)(kw + kr2) * HD_ + kp2 * 8, Kn + (t + 512) * 8);
      gload16(Kp + (size_t)(kw + kr3) * HD_ + kp3 * 8, Kn + (t + 768) * 8);
      nv00 = *(const us8v*)(Vp + (size_t)(kw + lane) * HD_ + oct0 * 8);
      nv01 = *(const us8v*)(Vp + (size_t)(kw + lane) * HD_ + oct1 * 8);
      nv10 = *(const us8v*)(Vp + (size_t)(kw + lane + 64) * HD_ + oct0 * 8);
      nv11 = *(const us8v*)(Vp + (size_t)(kw + lane + 64) * HD_ + oct1 * 8);
    }

    const int t0 = 2 * e, t1 = 2 * e + 1;
    const bool act0 = t0 < myNt, act1 = t1 < myNt;
    if (act0) {
      // S^T: s4t[h][s*4+c][j] = S[q=qt0+16h+r16][kv = e*128 + s*64 + 16c + 4g + j]
      f32x4 s4t[2][8];
      #pragma unroll
      for (int c = 0; c < 4; ++c)
        #pragma unroll
        for (int kk = 0; kk < 2; ++kk) {
          int r = c * 16 + r16;
          int ps = (kk * 4 + g) ^ (r & 7);
          bf16x8 kf = *(const bf16x8*)(Kl + r * 64 + ps * 8);
          if (kk == 0) { s4t[0][c] = mfma16(kf, qf[0][0], (f32x4){0,0,0,0});
                         s4t[1][c] = mfma16(kf, qf[1][0], (f32x4){0,0,0,0}); }
          else         { s4t[0][c] = mfma16(kf, qf[0][1], s4t[0][c]);
                         s4t[1][c] = mfma16(kf, qf[1][1], s4t[1][c]); }
        }
      if (act1) {
        #pragma unroll
        for (int c = 0; c < 4; ++c)
          #pragma unroll
          for (int kk = 0; kk < 2; ++kk) {
            int r = 64 + c * 16 + r16;
            int ps = (kk * 4 + g) ^ (r & 7);
            bf16x8 kf = *(const bf16x8*)(Kl + r * 64 + ps * 8);
            if (kk == 0) { s4t[0][4 + c] = mfma16(kf, qf[0][0], (f32x4){0,0,0,0});
                           s4t[1][4 + c] = mfma16(kf, qf[1][0], (f32x4){0,0,0,0}); }
            else         { s4t[0][4 + c] = mfma16(kf, qf[0][1], s4t[0][4 + c]);
                           s4t[1][4 + c] = mfma16(kf, qf[1][1], s4t[1][4 + c]); }
          }
      } else {
        #pragma unroll
        for (int h = 0; h < 2; ++h)
          #pragma unroll
          for (int c = 0; c < 4; ++c)
            s4t[h][4 + c] = (f32x4){-1e30f, -1e30f, -1e30f, -1e30f};
      }
      // diagonal masking (subtile-local col = 16c+4g+j vs tile-local row qloc)
      if (t0 == myNt - 1 || (act1 && t1 == myNt - 1)) {
        const int dsub = (t0 == myNt - 1) ? 0 : 4;
        #pragma unroll
        for (int h = 0; h < 2; ++h) {
          int qloc = halfsel * 32 + h * 16 + r16;
          #pragma unroll
          for (int c = 0; c < 4; ++c)
            #pragma unroll
            for (int j = 0; j < 4; ++j)
              if (c * 16 + g * 4 + j > qloc) s4t[h][dsub + c][j] = -1e30f;
        }
      }
      // unified online softmax over 128 cols per half
      bf16x8 pf[2][2][2];   // [h][sub][kk]
      #pragma unroll
      for (int h = 0; h < 2; ++h) {
        float mx = -1e30f;
        #pragma unroll
        for (int c = 0; c < 8; ++c)
          #pragma unroll
          for (int j = 0; j < 4; ++j) mx = fmaxf(mx, s4t[h][c][j]);
        mx = fmaxf(mx, __shfl_xor(mx, 16));
        mx = fmaxf(mx, __shfl_xor(mx, 32));
        float mn = fmaxf(mrun[h], mx);
        float alpha = __expf(mrun[h] - mn);
        mrun[h] = mn;
        float rs = 0.f;
        #pragma unroll
        for (int c = 0; c < 8; ++c)
          #pragma unroll
          for (int j = 0; j < 4; ++j) {
            float p = __expf(s4t[h][c][j] - mn);
            s4t[h][c][j] = p;
            rs += p;
          }
        rs += __shfl_xor(rs, 16);
        rs += __shfl_xor(rs, 32);
        lrun[h] = lrun[h] * alpha + rs;
        #pragma unroll
        for (int c = 0; c < 4; ++c)
          #pragma unroll
          for (int j = 0; j < 4; ++j) o[h][c][j] *= alpha;
        // P^T fragments: p[4hh+e] = s4t[h][s*4 + 2kk+hh][e]
        #pragma unroll
        for (int s = 0; s < 2; ++s)
          #pragma unroll
          for (int kk = 0; kk < 2; ++kk) {
            bf16x8 p;
            #pragma unroll
            for (int j = 0; j < 4; ++j) {
              p[j]     = (__bf16)s4t[h][s * 4 + 2 * kk][j];
              p[4 + j] = (__bf16)s4t[h][s * 4 + 2 * kk + 1][j];
            }
            pf[h][s][kk] = p;
          }
      }
      // O^T += V^T @ P^T : 1 vf read feeds 2 MFMAs (h=0,1)
      #pragma unroll
      for (int c = 0; c < 4; ++c) {
        int rv = c * 16 + r16;
        #pragma unroll
        for (int kk = 0; kk < 2; ++kk) {
          int slot = (4 * kk + g) ^ (r16 & 7);
          bf16x8 vf = *(const bf16x8*)(Vt + rv * 128 + slot * 8);
          o[0][c] = mfma16(vf, pf[0][0][kk], o[0][c]);
          o[1][c] = mfma16(vf, pf[1][0][kk], o[1][c]);
        }
      }
      if (act1) {
        #pragma unroll
        for (int c = 0; c < 4; ++c) {
          int rv = c * 16 + r16;
          #pragma unroll
          for (int kk = 0; kk < 2; ++kk) {
            int slot = (4 * kk + g) ^ (r16 & 7);
            bf16x8 vf = *(const bf16x8*)(Vt + rv * 128 + 64 + slot * 8);
            o[0][c] = mfma16(vf, pf[0][1][kk], o[0][c]);
            o[1][c] = mfma16(vf, pf[1][1][kk], o[1][c]);
          }
        }
      }
    }
  }

  // epilogue: dead K buffer (last read fenced by final epoch's barrier)
  const int deadK = ((epochs - 1) & 1) ^ 1;
  unsigned short* ep = LDS + deadK * 8192 + w4 * 1024;
  #pragma unroll
  for (int h = 0; h < 2; ++h) {
    float inv = 1.f / lrun[h];
    #pragma unroll
    for (int c = 0; c < 4; ++c) {
      us4v pk;
      #pragma unroll
      for (int j = 0; j < 4; ++j) pk[j] = f2bf(o[h][c][j] * inv);
      int slot = (4 * c + g) ^ r16;
      *(us4v*)(ep + r16 * 64 + slot * 4) = pk;
    }
    asm volatile("s_waitcnt lgkmcnt(0)" ::: "memory");
    __builtin_amdgcn_sched_barrier(0);
    {
      int q = lane >> 2, seg = lane & 3;
      us4v a0 = *(const us4v*)(ep + q * 64 + (((seg * 4 + 0) ^ q) & 15) * 4);
      us4v a1 = *(const us4v*)(ep + q * 64 + (((seg * 4 + 1) ^ q) & 15) * 4);
      us4v a2 = *(const us4v*)(ep + q * 64 + (((seg * 4 + 2) ^ q) & 15) * 4);
      us4v a3 = *(const us4v*)(ep + q * 64 + (((seg * 4 + 3) ^ q) & 15) * 4);
      us8v o0 = {a0[0],a0[1],a0[2],a0[3],a1[0],a1[1],a1[2],a1[3]};
      us8v o1 = {a2[0],a2[1],a2[2],a2[3],a3[0],a3[1],a3[2],a3[3]};
      size_t rowg = (size_t)(bh >> 4) * T_ + qt0 + h * 16 + q;
      int colg = (bh & 15) * 64 + seg * 16;
      *(us8v*)(ao + rowg * C_ + colg)     = o0;
      *(us8v*)(ao + rowg * C_ + colg + 8) = o1;
    }
    asm volatile("s_waitcnt lgkmcnt(0)" ::: "memory");
    __builtin_amdgcn_sched_barrier(0);
  }
}

// ---------------- launch ----------------
extern "C" void kernel_launch(void* const* d_in, const int* in_sizes, int n_in,
                              void* d_out, int out_size, void* d_ws, size_t ws_size,
                              hipStream_t stream) {
  const float* x      = (const float*)d_in[0];
  const float* w_qkv  = (const float*)d_in[1];
  const float* w_proj = (const float*)d_in[2];
  float* out = (float*)d_out;
  char* ws = (char*)d_ws;

  unsigned short* xb     = (unsigned short*)(ws);              // 8 MB (reused as ao)
  unsigned short* wqkvT  = (unsigned short*)(ws + 8388608);    // 6 MB
  unsigned short* wprojT = (unsigned short*)(ws + 14680064);   // 2 MB
  unsigned short* qb     = (unsigned short*)(ws + 16777216);   // 8 MB
  unsigned short* kb     = (unsigned short*)(ws + 25165824);   // 8 MB
  unsigned short* vb     = (unsigned short*)(ws + 33554432);   // 8 MB
  unsigned short* ao     = xb;

  cast_x_kernel<<<4096, 256, 0, stream>>>((const float4*)x, (us4v*)xb);
  transpose_cast_kernel<<<dim3(3 * C_ / 32, C_ / 32), dim3(32, 8), 0, stream>>>(
      w_qkv, wqkvT, C_, 3 * C_);
  transpose_cast_kernel<<<dim3(C_ / 32, C_ / 32), dim3(32, 8), 0, stream>>>(
      w_proj, wprojT, C_, C_);
  gemm_qkv_kernel<<<dim3(3 * C_ / 128, (B_ * T_) / 128), 256, 0, stream>>>(
      xb, wqkvT, qb, kb, vb);
  attn_kernel<<<dim3(16, 32), 256, 0, stream>>>(qb, kb, vb, ao);
  gemm_proj_kernel<<<dim3(C_ / 128, (B_ * T_) / 128), 256, 0, stream>>>(
      ao, wprojT, out);
}

// Round 10
// 123.360 us; speedup vs baseline: 1.6855x; 1.6855x over previous
//
#include <hip/hip_runtime.h>
#include <hip/hip_bf16.h>
#include <stdint.h>

typedef __bf16 bf16x8 __attribute__((ext_vector_type(8)));
typedef float f32x4 __attribute__((ext_vector_type(4)));
typedef unsigned short us4v __attribute__((ext_vector_type(4)));
typedef unsigned short us8v __attribute__((ext_vector_type(8)));

#define B_   2
#define T_   2048
#define C_   1024
#define NH_  16
#define HD_  64

__device__ __forceinline__ unsigned short f2bf(float f) {
  unsigned int u = __builtin_bit_cast(unsigned int, f);
  u += 0x7fffu + ((u >> 16) & 1u);           // RNE
  return (unsigned short)(u >> 16);
}
__device__ __forceinline__ float bf2f(unsigned short u) {
  unsigned int x = ((unsigned int)u) << 16;
  return __builtin_bit_cast(float, x);
}

__device__ __forceinline__ void gload16(const void* g, void* l) {
  __builtin_amdgcn_global_load_lds(
      (const __attribute__((address_space(1))) unsigned int*)g,
      (__attribute__((address_space(3))) unsigned int*)l, 16, 0, 0);
}

__device__ __forceinline__ f32x4 mfma16(bf16x8 a, bf16x8 b, f32x4 c) {
  return __builtin_amdgcn_mfma_f32_16x16x32_bf16(a, b, c, 0, 0, 0);
}

// ---------------- cast / transpose ----------------
__global__ __launch_bounds__(256) void cast_x_kernel(const float4* __restrict__ in,
                                                     us4v* __restrict__ out) {
  int i = blockIdx.x * 256 + threadIdx.x;
  float4 f = in[i];
  us4v o; o[0] = f2bf(f.x); o[1] = f2bf(f.y); o[2] = f2bf(f.z); o[3] = f2bf(f.w);
  out[i] = o;
}

// w: (K x N) fp32 row-major  ->  wT: (N x K) bf16 row-major
__global__ __launch_bounds__(256) void transpose_cast_kernel(const float* __restrict__ w,
                                                             unsigned short* __restrict__ wT,
                                                             int K, int N) {
  __shared__ float tile[32][33];
  int n0 = blockIdx.x * 32, k0 = blockIdx.y * 32;
  int tx = threadIdx.x, ty = threadIdx.y;   // 32 x 8
  #pragma unroll
  for (int i = 0; i < 4; ++i)
    tile[ty + 8*i][tx] = w[(size_t)(k0 + ty + 8*i) * N + n0 + tx];
  __syncthreads();
  #pragma unroll
  for (int i = 0; i < 4; ++i)
    wT[(size_t)(n0 + ty + 8*i) * K + k0 + tx] = f2bf(tile[tx][ty + 8*i]);
}

// ---------------- GEMM core (verified round 0) ----------------
__device__ __forceinline__ void gemm_core(const unsigned short* __restrict__ A,
                                          const unsigned short* __restrict__ Bt,
                                          int K, int m0, int n0,
                                          unsigned short* lA, unsigned short* lB,
                                          f32x4 acc[4][4]) {
  const int t = threadIdx.x;
  const int lane = t & 63, w = t >> 6;
  const int wm = w >> 1, wn = w & 1;
  const int g = lane >> 4, r16 = lane & 15;
  #pragma unroll
  for (int i = 0; i < 4; ++i)
    #pragma unroll
    for (int j = 0; j < 4; ++j) acc[i][j] = (f32x4){0.f, 0.f, 0.f, 0.f};

  for (int k0 = 0; k0 < K; k0 += 64) {
    #pragma unroll
    for (int i = 0; i < 4; ++i) {
      int slot = i * 256 + t;
      int r = slot >> 3, p = slot & 7;
      int q = p ^ (r & 7);
      gload16(A  + (size_t)(m0 + r) * K + k0 + q * 8, lA + slot * 8);
      gload16(Bt + (size_t)(n0 + r) * K + k0 + q * 8, lB + slot * 8);
    }
    asm volatile("s_waitcnt vmcnt(0)" ::: "memory");
    __syncthreads();

    bf16x8 af[4][2], bfr[4][2];
    #pragma unroll
    for (int mi = 0; mi < 4; ++mi)
      #pragma unroll
      for (int kk = 0; kk < 2; ++kk) {
        int r = wm * 64 + mi * 16 + r16;
        int ps = (kk * 4 + g) ^ (r & 7);
        af[mi][kk] = *(const bf16x8*)(lA + r * 64 + ps * 8);
      }
    #pragma unroll
    for (int ni = 0; ni < 4; ++ni)
      #pragma unroll
      for (int kk = 0; kk < 2; ++kk) {
        int r = wn * 64 + ni * 16 + r16;
        int ps = (kk * 4 + g) ^ (r & 7);
        bfr[ni][kk] = *(const bf16x8*)(lB + r * 64 + ps * 8);
      }
    #pragma unroll
    for (int mi = 0; mi < 4; ++mi)
      #pragma unroll
      for (int ni = 0; ni < 4; ++ni)
        #pragma unroll
        for (int kk = 0; kk < 2; ++kk)
          acc[mi][ni] = mfma16(af[mi][kk], bfr[ni][kk], acc[mi][ni]);
    __syncthreads();
  }
}

// XCD-aware bijective swizzle of the linear workgroup id (nwg % 8 == 0)
__device__ __forceinline__ int xcd_swz(int flat, int nwg) {
  int cpx = nwg >> 3;
  return (flat & 7) * cpx + (flat >> 3);
}

__global__ __launch_bounds__(256) void gemm_qkv_kernel(const unsigned short* __restrict__ xb,
                                                       const unsigned short* __restrict__ wT,
                                                       unsigned short* __restrict__ qb,
                                                       unsigned short* __restrict__ kb,
                                                       unsigned short* __restrict__ vb) {
  __shared__ unsigned short lA[128 * 64];
  __shared__ unsigned short lB[128 * 64];
  f32x4 acc[4][4];
  const int nbx = 3 * C_ / 128;
  int flat = xcd_swz(blockIdx.y * nbx + blockIdx.x, nbx * ((B_ * T_) / 128));
  const int m0 = (flat / nbx) * 128, n0 = (flat % nbx) * 128;
  gemm_core(xb, wT, C_, m0, n0, lA, lB, acc);
  const int t = threadIdx.x, lane = t & 63, w = t >> 6;
  const int wm = w >> 1, wn = w & 1, g = lane >> 4, r16 = lane & 15;
  #pragma unroll
  for (int mi = 0; mi < 4; ++mi)
    #pragma unroll
    for (int ni = 0; ni < 4; ++ni)
      #pragma unroll
      for (int j = 0; j < 4; ++j) {
        int gm = m0 + wm * 64 + mi * 16 + g * 4 + j;
        int gn = n0 + wn * 64 + ni * 16 + r16;
        int b = gm >> 11, tt = gm & 2047;
        int s = gn >> 10, rem = gn & 1023;
        int h = rem >> 6, d = rem & 63;
        unsigned short val = f2bf(acc[mi][ni][j]);
        size_t idx = ((size_t)(b * NH_ + h) * T_ + tt) * HD_ + d;
        if (s == 0)      qb[idx] = val;
        else if (s == 1) kb[idx] = val;
        else             vb[idx] = val;
      }
}

__global__ __launch_bounds__(256) void gemm_proj_kernel(const unsigned short* __restrict__ ab,
                                                        const unsigned short* __restrict__ wT,
                                                        float* __restrict__ out) {
  __shared__ unsigned short lA[128 * 64];
  __shared__ unsigned short lB[128 * 64];
  f32x4 acc[4][4];
  const int nbx = C_ / 128;
  int flat = xcd_swz(blockIdx.y * nbx + blockIdx.x, nbx * ((B_ * T_) / 128));
  const int m0 = (flat / nbx) * 128, n0 = (flat % nbx) * 128;
  gemm_core(ab, wT, C_, m0, n0, lA, lB, acc);
  const int t = threadIdx.x, lane = t & 63, w = t >> 6;
  const int wm = w >> 1, wn = w & 1, g = lane >> 4, r16 = lane & 15;
  #pragma unroll
  for (int mi = 0; mi < 4; ++mi)
    #pragma unroll
    for (int ni = 0; ni < 4; ++ni)
      #pragma unroll
      for (int j = 0; j < 4; ++j) {
        int gm = m0 + wm * 64 + mi * 16 + g * 4 + j;
        int gn = n0 + wn * 64 + ni * 16 + r16;
        out[(size_t)gm * C_ + gn] = acc[mi][ni][j];
      }
}

// ---------------- Flash attention v10: KV-split ----------------
// Block = one 64-row q-tile x one kv-window (<=16 tiles). 4 waves x 16 q-rows,
// 256 thr. Datapath = verified v5/v7 per-wave math verbatim (K gload_lds dbuf,
// V conflict-free reg->LDS transposed dbuf). Tiles 0..15: one full block.
// Tiles 16..31: half-A (kv [0,16)) + half-B (kv [16, tile+1)); both write
// NORMALIZED bf16 partials + (m,l); merge kernel combines.
// blockIdx.x: [0,16) halfA tile=16+bx | [16,32) halfB tile=47-bx | [32,48) full tile=47-bx.
// LDS (us): K0 [0,4096) K1 [4096,8192) V0 [8192,12288) V1 [12288,16384).
__global__ __launch_bounds__(256, 4) void attn_kernel(const unsigned short* __restrict__ qb,
                                                      const unsigned short* __restrict__ kb,
                                                      const unsigned short* __restrict__ vb,
                                                      unsigned short* __restrict__ ao,
                                                      unsigned short* __restrict__ partB,
                                                      float* __restrict__ mlbuf) {
  __shared__ unsigned short LDS[16384];
  const int bx = blockIdx.x, bh = blockIdx.y;
  int tile, kvLo, kvHi, mode;   // mode: 0=full, 1=halfA, 2=halfB
  if (bx < 16)      { tile = 16 + bx; kvLo = 0;  kvHi = 16;       mode = 1; }
  else if (bx < 32) { tile = 47 - bx; kvLo = 16; kvHi = tile + 1; mode = 2; }
  else              { tile = 47 - bx; kvLo = 0;  kvHi = tile + 1; mode = 0; }
  const int qt0 = tile * 64;
  const int t = threadIdx.x, lane = t & 63, w4 = t >> 6;   // w4 in 0..3
  const int g = lane >> 4, r16 = lane & 15;

  const unsigned short* Q  = qb + (size_t)bh * (T_ * HD_);
  const unsigned short* Kp = kb + (size_t)bh * (T_ * HD_);
  const unsigned short* Vp = vb + (size_t)bh * (T_ * HD_);

  // Q fragments (B-operand: lane holds Q[q=r16][k-octet g]), pre-scaled 1/8
  bf16x8 qf[2];
  {
    int qrow = qt0 + w4 * 16 + r16;
    #pragma unroll
    for (int kk = 0; kk < 2; ++kk) {
      us8v raw = *(const us8v*)(Q + (size_t)qrow * HD_ + kk * 32 + g * 8);
      bf16x8 qv;
      #pragma unroll
      for (int j = 0; j < 8; ++j) qv[j] = (__bf16)(bf2f(raw[j]) * 0.125f);
      qf[kk] = qv;
    }
  }

  f32x4 o[4];
  #pragma unroll
  for (int c = 0; c < 4; ++c) o[c] = (f32x4){0.f, 0.f, 0.f, 0.f};
  float mrun = -__builtin_inff(), lrun = 0.f;

  // staging constants (v7-verified formulas)
  const int kr0 = t >> 3,         kp0 = (t & 7) ^ (kr0 & 7);   // rows 0..31
  const int kr1 = (t + 256) >> 3, kp1 = (t & 7) ^ (kr1 & 7);   // rows 32..63
  // V: wave w4 owns d-rows [16w4,16w4+16), lane owns kv row `lane`.
  const int colp = (lane & 32) | ((lane & 12) << 1) | ((lane >> 2) & 4) | (lane & 3);
  const int cslot = colp >> 3, cwithin = colp & 7;

  // prologue: tile kvLo
  gload16(Kp + (size_t)(kvLo * 64 + kr0) * HD_ + kp0 * 8, LDS + t * 8);
  gload16(Kp + (size_t)(kvLo * 64 + kr1) * HD_ + kp1 * 8, LDS + (t + 256) * 8);
  us8v nv0 = *(const us8v*)(Vp + (size_t)(kvLo * 64 + lane) * HD_ + w4 * 16);
  us8v nv1 = *(const us8v*)(Vp + (size_t)(kvLo * 64 + lane) * HD_ + w4 * 16 + 8);

  for (int it = kvLo; it < kvHi; ++it) {
    const int cur = (it - kvLo) & 1;
    const unsigned short* Kl = LDS + cur * 4096;
    unsigned short* Vt = LDS + 8192 + cur * 4096;

    asm volatile("s_waitcnt vmcnt(0)" ::: "memory");   // K[it] in LDS, V[it] in regs
    #pragma unroll
    for (int u = 0; u < 8; ++u) {
      int d = w4 * 16 + u;                             // d&7 == u
      Vt[d * 64 + ((cslot ^ u) << 3) + cwithin] = nv0[u];
    }
    #pragma unroll
    for (int u = 0; u < 8; ++u) {
      int d = w4 * 16 + 8 + u;
      Vt[d * 64 + ((cslot ^ u) << 3) + cwithin] = nv1[u];
    }
    __syncthreads();

    if (it + 1 < kvHi) {    // issue next-tile loads (land in buf cur^1)
      const int kv0n = (it + 1) * 64;
      unsigned short* Kn = LDS + (cur ^ 1) * 4096;
      gload16(Kp + (size_t)(kv0n + kr0) * HD_ + kp0 * 8, Kn + t * 8);
      gload16(Kp + (size_t)(kv0n + kr1) * HD_ + kp1 * 8, Kn + (t + 256) * 8);
      nv0 = *(const us8v*)(Vp + (size_t)(kv0n + lane) * HD_ + w4 * 16);
      nv1 = *(const us8v*)(Vp + (size_t)(kv0n + lane) * HD_ + w4 * 16 + 8);
    }

    {
      // S^T = K @ Q^T : s4t[c][j] = S[q=r16-row][kv = it*64 + 16c + 4g + j]
      f32x4 s4t[4];
      #pragma unroll
      for (int c = 0; c < 4; ++c) s4t[c] = (f32x4){0.f, 0.f, 0.f, 0.f};
      #pragma unroll
      for (int c = 0; c < 4; ++c)
        #pragma unroll
        for (int kk = 0; kk < 2; ++kk) {
          int r = c * 16 + r16;
          int ps = (kk * 4 + g) ^ (r & 7);
          bf16x8 kf = *(const bf16x8*)(Kl + r * 64 + ps * 8);
          s4t[c] = mfma16(kf, qf[kk], s4t[c]);
        }
      if (it == tile) {   // diagonal tile: mask kv_local > q_local
        int qloc = w4 * 16 + r16;
        #pragma unroll
        for (int c = 0; c < 4; ++c)
          #pragma unroll
          for (int j = 0; j < 4; ++j)
            if (c * 16 + g * 4 + j > qloc) s4t[c][j] = -1e30f;
      }
      // online softmax: row q=r16 lane-local across 16 regs + 4 lanes (xor 16,32)
      float mx = -1e30f;
      #pragma unroll
      for (int c = 0; c < 4; ++c)
        #pragma unroll
        for (int j = 0; j < 4; ++j) mx = fmaxf(mx, s4t[c][j]);
      mx = fmaxf(mx, __shfl_xor(mx, 16));
      mx = fmaxf(mx, __shfl_xor(mx, 32));
      float mn = fmaxf(mrun, mx);
      float alpha = __expf(mrun - mn);
      mrun = mn;
      float rs = 0.f;
      #pragma unroll
      for (int c = 0; c < 4; ++c)
        #pragma unroll
        for (int j = 0; j < 4; ++j) {
          float p = __expf(s4t[c][j] - mn);
          s4t[c][j] = p;
          rs += p;
        }
      rs += __shfl_xor(rs, 16);
      rs += __shfl_xor(rs, 32);
      lrun = lrun * alpha + rs;
      #pragma unroll
      for (int c = 0; c < 4; ++c)
        #pragma unroll
        for (int j = 0; j < 4; ++j) o[c][j] *= alpha;

      // P^T fragments in-register (B-operand): p[4h+e] = s4t[2kk+h][e]
      bf16x8 pf[2];
      #pragma unroll
      for (int kk = 0; kk < 2; ++kk) {
        bf16x8 p;
        #pragma unroll
        for (int j = 0; j < 4; ++j) {
          p[j]     = (__bf16)s4t[2 * kk][j];
          p[4 + j] = (__bf16)s4t[2 * kk + 1][j];
        }
        pf[kk] = p;
      }
      // O^T += V^T @ P^T : A-fragment = swizzled b128 from Vt
      #pragma unroll
      for (int c = 0; c < 4; ++c) {
        int rv = c * 16 + r16;
        #pragma unroll
        for (int kk = 0; kk < 2; ++kk) {
          int slot = (4 * kk + g) ^ (r16 & 7);
          bf16x8 vf = *(const bf16x8*)(Vt + rv * 64 + slot * 8);
          o[c] = mfma16(vf, pf[kk], o[c]);
        }
      }
    }
  }

  // write (m,l) for split halves (rows lane-owned by g==0 lanes)
  if (mode && g == 0) {
    int prow = (bh * 16 + (tile - 16)) * 64 + w4 * 16 + r16;
    float* mlp = mlbuf + (size_t)prow * 4;
    if (mode == 1) { mlp[0] = mrun; mlp[1] = lrun; }
    else           { mlp[2] = mrun; mlp[3] = lrun; }
  }

  // epilogue: normalized O -> dead K buffer transpose -> coalesced store
  const int deadK = ((kvHi - kvLo - 1) & 1) ^ 1;
  unsigned short* ep = LDS + deadK * 4096 + w4 * 1024;
  float inv = 1.f / lrun;
  #pragma unroll
  for (int c = 0; c < 4; ++c) {
    us4v pk;
    #pragma unroll
    for (int j = 0; j < 4; ++j) pk[j] = f2bf(o[c][j] * inv);
    int slot = (4 * c + g) ^ r16;
    *(us4v*)(ep + r16 * 64 + slot * 4) = pk;
  }
  asm volatile("s_waitcnt lgkmcnt(0)" ::: "memory");
  __builtin_amdgcn_sched_barrier(0);
  {
    int q = lane >> 2, seg = lane & 3;
    us4v a0 = *(const us4v*)(ep + q * 64 + (((seg * 4 + 0) ^ q) & 15) * 4);
    us4v a1 = *(const us4v*)(ep + q * 64 + (((seg * 4 + 1) ^ q) & 15) * 4);
    us4v a2 = *(const us4v*)(ep + q * 64 + (((seg * 4 + 2) ^ q) & 15) * 4);
    us4v a3 = *(const us4v*)(ep + q * 64 + (((seg * 4 + 3) ^ q) & 15) * 4);
    us8v o0 = {a0[0],a0[1],a0[2],a0[3],a1[0],a1[1],a1[2],a1[3]};
    us8v o1 = {a2[0],a2[1],a2[2],a2[3],a3[0],a3[1],a3[2],a3[3]};
    if (mode != 2) {
      size_t rowg = (size_t)(bh >> 4) * T_ + qt0 + w4 * 16 + q;
      int colg = (bh & 15) * 64 + seg * 16;
      *(us8v*)(ao + rowg * C_ + colg)     = o0;
      *(us8v*)(ao + rowg * C_ + colg + 8) = o1;
    } else {
      size_t prow = (size_t)(bh * 16 + (tile - 16)) * 64 + w4 * 16 + q;
      *(us8v*)(partB + prow * 64 + seg * 16)     = o0;
      *(us8v*)(partB + prow * 64 + seg * 16 + 8) = o1;
    }
  }
}

// ---------------- merge kernel: combine halfA (in ao) with halfB ----------------
__global__ __launch_bounds__(256) void attn_merge_kernel(unsigned short* __restrict__ ao,
                                                         const unsigned short* __restrict__ partB,
                                                         const float* __restrict__ mlbuf) {
  const int blk = blockIdx.x;          // 512 = 32 bh x 16 ti
  const int bh = blk >> 4, ti = blk & 15;
  const int t = threadIdx.x;
  const int row = t >> 2, seg = t & 3;
  const size_t prow = (size_t)(bh * 16 + ti) * 64 + row;
  const float* mlp = mlbuf + prow * 4;
  float mA = mlp[0], lA = mlp[1], mB = mlp[2], lB = mlp[3];
  float m = fmaxf(mA, mB);
  float wA = lA * __expf(mA - m), wB = lB * __expf(mB - m);
  float rinv = 1.f / (wA + wB);
  wA *= rinv; wB *= rinv;
  size_t rowg = (size_t)(bh >> 4) * T_ + (16 + ti) * 64 + row;
  unsigned short* aop = ao + rowg * C_ + (bh & 15) * 64 + seg * 16;
  const unsigned short* obp = partB + prow * 64 + seg * 16;
  us8v oa0 = *(const us8v*)(aop);
  us8v oa1 = *(const us8v*)(aop + 8);
  us8v ob0 = *(const us8v*)(obp);
  us8v ob1 = *(const us8v*)(obp + 8);
  us8v r0, r1;
  #pragma unroll
  for (int j = 0; j < 8; ++j) {
    r0[j] = f2bf(bf2f(oa0[j]) * wA + bf2f(ob0[j]) * wB);
    r1[j] = f2bf(bf2f(oa1[j]) * wA + bf2f(ob1[j]) * wB);
  }
  *(us8v*)(aop)     = r0;
  *(us8v*)(aop + 8) = r1;
}

// ---------------- launch ----------------
extern "C" void kernel_launch(void* const* d_in, const int* in_sizes, int n_in,
                              void* d_out, int out_size, void* d_ws, size_t ws_size,
                              hipStream_t stream) {
  const float* x      = (const float*)d_in[0];
  const float* w_qkv  = (const float*)d_in[1];
  const float* w_proj = (const float*)d_in[2];
  float* out = (float*)d_out;
  char* ws = (char*)d_ws;

  unsigned short* xb     = (unsigned short*)(ws);              // 8 MB (reused as ao)
  unsigned short* wqkvT  = (unsigned short*)(ws + 8388608);    // 6 MB (reused: partB+ml)
  unsigned short* wprojT = (unsigned short*)(ws + 14680064);   // 2 MB
  unsigned short* qb     = (unsigned short*)(ws + 16777216);   // 8 MB
  unsigned short* kb     = (unsigned short*)(ws + 25165824);   // 8 MB
  unsigned short* vb     = (unsigned short*)(ws + 33554432);   // 8 MB
  unsigned short* ao     = xb;
  // partials live in the wqkvT region (dead after gemm_qkv):
  unsigned short* partB  = wqkvT;                              // 4 MB (32*16*64 rows x 64 d)
  float*          mlbuf  = (float*)(ws + 8388608 + 4194304);   // 512 KB (rows x 4 f32)

  cast_x_kernel<<<4096, 256, 0, stream>>>((const float4*)x, (us4v*)xb);
  transpose_cast_kernel<<<dim3(3 * C_ / 32, C_ / 32), dim3(32, 8), 0, stream>>>(
      w_qkv, wqkvT, C_, 3 * C_);
  transpose_cast_kernel<<<dim3(C_ / 32, C_ / 32), dim3(32, 8), 0, stream>>>(
      w_proj, wprojT, C_, C_);
  gemm_qkv_kernel<<<dim3(3 * C_ / 128, (B_ * T_) / 128), 256, 0, stream>>>(
      xb, wqkvT, qb, kb, vb);
  attn_kernel<<<dim3(48, 32), 256, 0, stream>>>(qb, kb, vb, ao, partB, mlbuf);
  attn_merge_kernel<<<512, 256, 0, stream>>>(ao, partB, mlbuf);
  gemm_proj_kernel<<<dim3(C_ / 128, (B_ * T_) / 128), 256, 0, stream>>>(
      ao, wprojT, out);
}